// Round 5
// baseline (12791.585 us; speedup 1.0000x reference)
//
#include <hip/hip_runtime.h>
#include <cstdint>
#include <cstddef>

#define N_NODES 50000
#define N_EDGES 800000
#define F_IN_D 100
#define HDIM 128
#define CDIM 10

// ---------------- preprocessing ----------------

__global__ void prep_convert_kernel(const int* __restrict__ ei, int* __restrict__ row32,
                                    int* __restrict__ col32, int E) {
  // Detect int64 vs int32 storage: for int64 (values < 2^31), every high word is 0.
  bool is64 = true;
  for (int i = 0; i < 32; ++i) { if (ei[2 * i + 1] != 0) is64 = false; }
  int e = blockIdx.x * blockDim.x + threadIdx.x;
  if (e < E) {
    if (is64) { row32[e] = ei[2 * e]; col32[e] = ei[2 * (E + e)]; }
    else      { row32[e] = ei[e];     col32[e] = ei[E + e]; }
  }
}

__global__ void prep_degcnt_kernel(const int* __restrict__ col32, const float* __restrict__ w,
                                   float* __restrict__ deg, int* __restrict__ cnt, int E) {
  int e = blockIdx.x * blockDim.x + threadIdx.x;
  if (e < E) {
    int c = col32[e];
    atomicAdd(&deg[c], w[e]);
    atomicAdd(&cnt[c], 1);
  }
}

__global__ void prep_dis_kernel(const float* __restrict__ deg, float* __restrict__ dis, int n) {
  int i = blockIdx.x * blockDim.x + threadIdx.x;
  if (i < n) {
    float d = deg[i];
    dis[i] = d > 0.f ? rsqrtf(fmaxf(d, 1e-12f)) : 0.f;
  }
}

__global__ void prep_norm_kernel(const int* __restrict__ row32, const int* __restrict__ col32,
                                 const float* __restrict__ w, const float* __restrict__ dis,
                                 float* __restrict__ nrm, int E) {
  int e = blockIdx.x * blockDim.x + threadIdx.x;
  if (e < E) nrm[e] = dis[row32[e]] * w[e] * dis[col32[e]];
}

// block sums of cnt chunks (256 elems/block)
__global__ void prep_scanA_kernel(const int* __restrict__ cnt, int* __restrict__ partial, int n) {
  __shared__ int sd[256];
  int tid = threadIdx.x;
  int i = blockIdx.x * 256 + tid;
  sd[tid] = (i < n) ? cnt[i] : 0;
  __syncthreads();
  for (int s = 128; s > 0; s >>= 1) {
    if (tid < s) sd[tid] += sd[tid + s];
    __syncthreads();
  }
  if (tid == 0) partial[blockIdx.x] = sd[0];
}

// exclusive scan of block partials (nb <= 256), plus ptr[n] = total
__global__ void prep_scanB_kernel(int* __restrict__ partial, int* __restrict__ ptr, int nb, int n) {
  __shared__ int sd[256];
  int tid = threadIdx.x;
  int v = (tid < nb) ? partial[tid] : 0;
  sd[tid] = v;
  __syncthreads();
  for (int offd = 1; offd < 256; offd <<= 1) {
    int t = (tid >= offd) ? sd[tid - offd] : 0;
    __syncthreads();
    sd[tid] += t;
    __syncthreads();
  }
  if (tid < nb) partial[tid] = sd[tid] - v;   // exclusive
  if (tid == 255) ptr[n] = sd[255];
}

// per-chunk exclusive scan + block offset -> ptr, pos
__global__ void prep_scanC_kernel(const int* __restrict__ cnt, const int* __restrict__ partial,
                                  int* __restrict__ ptr, int* __restrict__ pos, int n) {
  __shared__ int sd[256];
  int tid = threadIdx.x;
  int i = blockIdx.x * 256 + tid;
  int v = (i < n) ? cnt[i] : 0;
  sd[tid] = v;
  __syncthreads();
  for (int offd = 1; offd < 256; offd <<= 1) {
    int t = (tid >= offd) ? sd[tid - offd] : 0;
    __syncthreads();
    sd[tid] += t;
    __syncthreads();
  }
  if (i < n) {
    int p = partial[blockIdx.x] + sd[tid] - v;
    ptr[i] = p;
    pos[i] = p;
  }
}

__global__ void prep_place_kernel(const int* __restrict__ row32, const int* __restrict__ col32,
                                  const float* __restrict__ nrm, int* __restrict__ pos,
                                  int* __restrict__ srcs, float* __restrict__ wsrt, int E) {
  int e = blockIdx.x * blockDim.x + threadIdx.x;
  if (e < E) {
    int c = col32[e];
    int slot = atomicAdd(&pos[c], 1);
    srcs[slot] = row32[e];
    wsrt[slot] = nrm[e];
  }
}

// ---------------- propagation hop, d=128, fused y-add (+ optional ELU) ----------------
// sout[n][:] = maybeELU( y[n][:] + sum_j w_j * sin[src_j][:] )
template <int TAG, bool ELU>
__global__ void hop128_kernel(const float* __restrict__ sin_, const float* __restrict__ y,
                              const int* __restrict__ ptr, const int* __restrict__ srcs,
                              const float* __restrict__ w, float* __restrict__ sout, int n) {
  int local = threadIdx.x >> 5;            // 8 nodes per 256-thread block
  int f4 = threadIdx.x & 31;               // float4 slot: covers 128 floats
  int node = blockIdx.x * 8 + local;
  if (node >= n) return;
  const float4* s4 = (const float4*)sin_;
  float4 acc = ((const float4*)y)[(size_t)node * 32 + f4];
  int b = ptr[node], e = ptr[node + 1];
  int j = b;
  for (; j + 1 < e; j += 2) {
    int s0 = srcs[j], s1 = srcs[j + 1];
    float w0 = w[j], w1 = w[j + 1];
    float4 v0 = s4[(size_t)s0 * 32 + f4];
    float4 v1 = s4[(size_t)s1 * 32 + f4];
    acc.x += w0 * v0.x + w1 * v1.x;
    acc.y += w0 * v0.y + w1 * v1.y;
    acc.z += w0 * v0.z + w1 * v1.z;
    acc.w += w0 * v0.w + w1 * v1.w;
  }
  if (j < e) {
    float w0 = w[j];
    float4 v0 = s4[(size_t)srcs[j] * 32 + f4];
    acc.x += w0 * v0.x; acc.y += w0 * v0.y; acc.z += w0 * v0.z; acc.w += w0 * v0.w;
  }
  if (ELU) {
    acc.x = acc.x > 0.f ? acc.x : expm1f(acc.x);
    acc.y = acc.y > 0.f ? acc.y : expm1f(acc.y);
    acc.z = acc.z > 0.f ? acc.z : expm1f(acc.z);
    acc.w = acc.w > 0.f ? acc.w : expm1f(acc.w);
  }
  ((float4*)sout)[(size_t)node * 32 + f4] = acc;
}

// d=10 hop with fused add:  out[n][f] = ybuf[n*64 + yOff + f] + sum_e w * z[s*zStride + zOff + f]
template <int TAG>
__global__ void hop10_kernel(const float* __restrict__ z, int zStride, int zOff,
                             const float* __restrict__ ybuf, int yOff,
                             const int* __restrict__ ptr, const int* __restrict__ srcs,
                             const float* __restrict__ wsrt, float* __restrict__ out, int n) {
  int local = threadIdx.x >> 4;            // 16 nodes per 256-thread block
  int f = threadIdx.x & 15;
  int node = blockIdx.x * 16 + local;
  if (node >= n || f >= CDIM) return;
  float acc = ybuf[(size_t)node * 64 + yOff + f];
  int b = ptr[node], e = ptr[node + 1];
  for (int j = b; j < e; ++j) {
    acc += wsrt[j] * z[(size_t)srcs[j] * zStride + zOff + f];
  }
  out[(size_t)node * CDIM + f] = acc;
}

// ---------------- dense GEMM ----------------
// out[n, c] = sum_k X[n,k] * B[k,c] (+bias)   64x64 tile, 256 threads, 4x4/thread
// BMODE 0: B[k,c] = W[k*128 + c], 128 cols (one hop-matrix slice)
// BMODE 1: B[k,c] = W3[(c/10)*K_DIM*10 + k*10 + c%10]  (c<60; 6 matrices concatenated)
template <int TAG, int K_DIM, int BMODE, bool ADD_BIAS>
__global__ void gemm_kernel(const float* __restrict__ X, const float* __restrict__ W,
                            const float* __restrict__ bias, float* __restrict__ out,
                            int n, int ostride) {
  __shared__ float xt[32][68];   // [k][node], padded (68*4=272B rows, 16B-aligned)
  __shared__ float bt[32][64];   // [k][col]
  const int tid = threadIdx.x;
  const int tx = tid & 15;       // node group
  const int ty = tid >> 4;       // col group
  const int n0 = blockIdx.x * 64;
  const int c0 = blockIdx.y * 64;
  float acc[4][4];
#pragma unroll
  for (int i = 0; i < 4; ++i)
#pragma unroll
    for (int j = 0; j < 4; ++j) acc[i][j] = 0.f;

  for (int k0 = 0; k0 < K_DIM; k0 += 32) {
#pragma unroll
    for (int i = 0; i < 8; ++i) {
      int idx = tid + i * 256;
      int nl = idx >> 5, kl = idx & 31;
      int nn = n0 + nl, kg = k0 + kl;
      float v = 0.f;
      if (nn < n && kg < K_DIM) v = X[(size_t)nn * K_DIM + kg];
      xt[kl][nl] = v;
    }
#pragma unroll
    for (int i = 0; i < 8; ++i) {
      int idx = tid + i * 256;
      int kl = idx >> 6, cl = idx & 63;
      int kg = k0 + kl, c = c0 + cl;
      float v = 0.f;
      if (BMODE == 0) {
        if (kg < K_DIM) v = W[(size_t)kg * 128 + c];
      } else {
        if (kg < K_DIM && cl < 6 * CDIM)
          v = W[(size_t)(cl / CDIM) * (K_DIM * CDIM) + (size_t)kg * CDIM + (cl % CDIM)];
      }
      bt[kl][cl] = v;
    }
    __syncthreads();
#pragma unroll
    for (int kk = 0; kk < 32; ++kk) {
      float4 xv = *(const float4*)&xt[kk][tx * 4];
      float4 bv = *(const float4*)&bt[kk][ty * 4];
      acc[0][0] += xv.x * bv.x; acc[0][1] += xv.x * bv.y; acc[0][2] += xv.x * bv.z; acc[0][3] += xv.x * bv.w;
      acc[1][0] += xv.y * bv.x; acc[1][1] += xv.y * bv.y; acc[1][2] += xv.y * bv.z; acc[1][3] += xv.y * bv.w;
      acc[2][0] += xv.z * bv.x; acc[2][1] += xv.z * bv.y; acc[2][2] += xv.z * bv.z; acc[2][3] += xv.z * bv.w;
      acc[3][0] += xv.w * bv.x; acc[3][1] += xv.w * bv.y; acc[3][2] += xv.w * bv.z; acc[3][3] += xv.w * bv.w;
    }
    __syncthreads();
  }
#pragma unroll
  for (int i = 0; i < 4; ++i) {
    int nn = n0 + tx * 4 + i;
    if (nn >= n) continue;
#pragma unroll
    for (int j = 0; j < 4; ++j) {
      int c = c0 + ty * 4 + j;
      float r = acc[i][j];
      if (ADD_BIAS) {
        if (BMODE == 0) r += bias[c];
        else if (c < CDIM) r += bias[c];
      }
      out[(size_t)nn * ostride + c] = r;
    }
  }
}

// ---------------- host ----------------

extern "C" void kernel_launch(void* const* d_in, const int* in_sizes, int n_in,
                              void* d_out, int out_size, void* d_ws, size_t ws_size,
                              hipStream_t stream) {
  const float* x  = (const float*)d_in[0];
  const int*   ei = (const int*)d_in[1];
  const float* ew = (const float*)d_in[2];
  const float* W1 = (const float*)d_in[3];
  const float* b1 = (const float*)d_in[4];
  const float* W2 = (const float*)d_in[5];
  const float* b2 = (const float*)d_in[6];
  const float* W3 = (const float*)d_in[7];
  const float* b3 = (const float*)d_in[8];
  float* out = (float*)d_out;

  const int N = N_NODES, E = N_EDGES;
  char* base = (char*)d_ws;
  size_t off = 0;
  auto alloc = [&](size_t bytes) -> char* {
    char* p = base + off;
    off += (bytes + 255) & ~(size_t)255;
    return p;
  };
  float* bufA = (float*)alloc((size_t)N * 128 * 4);
  float* bufB = (float*)alloc((size_t)N * 128 * 4);
  float* bufC = (float*)alloc((size_t)N * 128 * 4);
  float* bufD = (float*)alloc((size_t)N * 128 * 4);
  int*   ptrA = (int*)alloc((size_t)(N + 1) * 4);
  int*   pos  = (int*)alloc((size_t)N * 4);
  int*   srcs = (int*)alloc((size_t)E * 4);
  float* wsrt = (float*)alloc((size_t)E * 4);
  int*   part = (int*)alloc(256 * 4);

  // Preprocessing transients overlay bufA (bufA first written after preprocessing).
  char* t = (char*)bufA;
  int*   row32 = (int*)t;   t += (size_t)E * 4;
  int*   col32 = (int*)t;   t += (size_t)E * 4;
  float* nrm   = (float*)t; t += (size_t)E * 4;
  float* deg   = (float*)t; t += (size_t)N * 4;
  float* dis   = (float*)t; t += (size_t)N * 4;
  int*   cnt   = (int*)t;   t += (size_t)N * 4;

  hipMemsetAsync(deg, 0, (size_t)N * 4, stream);
  hipMemsetAsync(cnt, 0, (size_t)N * 4, stream);

  const int eb = (E + 255) / 256;
  const int nb = (N + 255) / 256;   // 196
  prep_convert_kernel<<<eb, 256, 0, stream>>>(ei, row32, col32, E);
  prep_degcnt_kernel<<<eb, 256, 0, stream>>>(col32, ew, deg, cnt, E);
  prep_dis_kernel<<<nb, 256, 0, stream>>>(deg, dis, N);
  prep_norm_kernel<<<eb, 256, 0, stream>>>(row32, col32, ew, dis, nrm, E);
  prep_scanA_kernel<<<nb, 256, 0, stream>>>(cnt, part, N);
  prep_scanB_kernel<<<1, 256, 0, stream>>>(part, ptrA, nb, N);
  prep_scanC_kernel<<<nb, 256, 0, stream>>>(cnt, part, ptrA, pos, N);
  prep_place_kernel<<<eb, 256, 0, stream>>>(row32, col32, nrm, pos, srcs, wsrt, E);

  const dim3 gemmGrid((N + 63) / 64, 2);
  const int hopBlocks = (N + 7) / 8;

  // ===== layer 1: in = x (K=100), Horner: s=y5; s=A*s+y_k; ELU at k=0 =====
  {
    const float* in = x;
    float* Y = bufA; float* P = bufB; float* Q = bufC;
    gemm_kernel<15, F_IN_D, 0, false><<<gemmGrid, 256, 0, stream>>>(in, W1 + (size_t)5 * F_IN_D * 128, b1, P, N, 128);
    gemm_kernel<14, F_IN_D, 0, false><<<gemmGrid, 256, 0, stream>>>(in, W1 + (size_t)4 * F_IN_D * 128, b1, Y, N, 128);
    hop128_kernel<14, false><<<hopBlocks, 256, 0, stream>>>(P, Y, ptrA, srcs, wsrt, Q, N);
    { float* tmp = P; P = Q; Q = tmp; }
    gemm_kernel<13, F_IN_D, 0, false><<<gemmGrid, 256, 0, stream>>>(in, W1 + (size_t)3 * F_IN_D * 128, b1, Y, N, 128);
    hop128_kernel<13, false><<<hopBlocks, 256, 0, stream>>>(P, Y, ptrA, srcs, wsrt, Q, N);
    { float* tmp = P; P = Q; Q = tmp; }
    gemm_kernel<12, F_IN_D, 0, false><<<gemmGrid, 256, 0, stream>>>(in, W1 + (size_t)2 * F_IN_D * 128, b1, Y, N, 128);
    hop128_kernel<12, false><<<hopBlocks, 256, 0, stream>>>(P, Y, ptrA, srcs, wsrt, Q, N);
    { float* tmp = P; P = Q; Q = tmp; }
    gemm_kernel<11, F_IN_D, 0, false><<<gemmGrid, 256, 0, stream>>>(in, W1 + (size_t)1 * F_IN_D * 128, b1, Y, N, 128);
    hop128_kernel<11, false><<<hopBlocks, 256, 0, stream>>>(P, Y, ptrA, srcs, wsrt, Q, N);
    { float* tmp = P; P = Q; Q = tmp; }
    gemm_kernel<10, F_IN_D, 0, true><<<gemmGrid, 256, 0, stream>>>(in, W1, b1, Y, N, 128);
    hop128_kernel<10, true><<<hopBlocks, 256, 0, stream>>>(P, Y, ptrA, srcs, wsrt, Q, N);
    // result (h1) in Q == bufC
  }

  // ===== layer 2: in = bufC (K=128) =====
  {
    const float* in = bufC;
    float* Y = bufA; float* P = bufB; float* Q = bufD;
    gemm_kernel<25, HDIM, 0, false><<<gemmGrid, 256, 0, stream>>>(in, W2 + (size_t)5 * HDIM * 128, b2, P, N, 128);
    gemm_kernel<24, HDIM, 0, false><<<gemmGrid, 256, 0, stream>>>(in, W2 + (size_t)4 * HDIM * 128, b2, Y, N, 128);
    hop128_kernel<24, false><<<hopBlocks, 256, 0, stream>>>(P, Y, ptrA, srcs, wsrt, Q, N);
    { float* tmp = P; P = Q; Q = tmp; }
    gemm_kernel<23, HDIM, 0, false><<<gemmGrid, 256, 0, stream>>>(in, W2 + (size_t)3 * HDIM * 128, b2, Y, N, 128);
    hop128_kernel<23, false><<<hopBlocks, 256, 0, stream>>>(P, Y, ptrA, srcs, wsrt, Q, N);
    { float* tmp = P; P = Q; Q = tmp; }
    gemm_kernel<22, HDIM, 0, false><<<gemmGrid, 256, 0, stream>>>(in, W2 + (size_t)2 * HDIM * 128, b2, Y, N, 128);
    hop128_kernel<22, false><<<hopBlocks, 256, 0, stream>>>(P, Y, ptrA, srcs, wsrt, Q, N);
    { float* tmp = P; P = Q; Q = tmp; }
    gemm_kernel<21, HDIM, 0, false><<<gemmGrid, 256, 0, stream>>>(in, W2 + (size_t)1 * HDIM * 128, b2, Y, N, 128);
    hop128_kernel<21, false><<<hopBlocks, 256, 0, stream>>>(P, Y, ptrA, srcs, wsrt, Q, N);
    { float* tmp = P; P = Q; Q = tmp; }
    gemm_kernel<20, HDIM, 0, true><<<gemmGrid, 256, 0, stream>>>(in, W2, b2, Y, N, 128);
    hop128_kernel<20, true><<<hopBlocks, 256, 0, stream>>>(P, Y, ptrA, srcs, wsrt, Q, N);
    // result (h2) in Q == bufD
  }

  // ===== layer 3: in = bufD, 128 -> 10 via Horner on projected y (BMODE1) =====
  {
    const float* in = bufD;
    float* ybuf = bufA;                                 // [N][64]: c = k*10+f
    float* z0 = bufB;
    float* z1 = (float*)((char*)bufB + (size_t)N * 16 * 4);
    dim3 g3((N + 63) / 64, 1);
    gemm_kernel<30, HDIM, 1, true><<<g3, 256, 0, stream>>>(in, W3, b3, ybuf, N, 64);
    int hb = (N + 15) / 16;
    hop10_kernel<35><<<hb, 256, 0, stream>>>(ybuf, 64, 50, ybuf, 40, ptrA, srcs, wsrt, z0, N);
    hop10_kernel<34><<<hb, 256, 0, stream>>>(z0, 10, 0, ybuf, 30, ptrA, srcs, wsrt, z1, N);
    hop10_kernel<33><<<hb, 256, 0, stream>>>(z1, 10, 0, ybuf, 20, ptrA, srcs, wsrt, z0, N);
    hop10_kernel<32><<<hb, 256, 0, stream>>>(z0, 10, 0, ybuf, 10, ptrA, srcs, wsrt, z1, N);
    hop10_kernel<31><<<hb, 256, 0, stream>>>(z1, 10, 0, ybuf, 0, ptrA, srcs, wsrt, out, N);
  }

  (void)in_sizes; (void)n_in; (void)out_size; (void)ws_size;
}

// Round 6
// 12760.252 us; speedup vs baseline: 1.0025x; 1.0025x over previous
//
#include <hip/hip_runtime.h>
#include <cstdint>
#include <cstddef>

#define N_NODES 50000
#define N_EDGES 800000
#define F_IN_D 100
#define HDIM 128
#define CDIM 10

// ---------------- preprocessing ----------------

// convert + degree-sum + degree-count in one pass
__global__ void prep_convert_kernel(const int* __restrict__ ei, const float* __restrict__ ew,
                                    int* __restrict__ row32, int* __restrict__ col32,
                                    float* __restrict__ deg, int* __restrict__ cnt, int E) {
  // Detect int64 vs int32 storage: for int64 (values < 2^31), every high word is 0.
  bool is64 = true;
  for (int i = 0; i < 32; ++i) { if (ei[2 * i + 1] != 0) is64 = false; }
  int e = blockIdx.x * blockDim.x + threadIdx.x;
  if (e < E) {
    int r, c;
    if (is64) { r = ei[2 * e]; c = ei[2 * (E + e)]; }
    else      { r = ei[e];     c = ei[E + e]; }
    row32[e] = r;
    col32[e] = c;
    atomicAdd(&deg[c], ew[e]);
    atomicAdd(&cnt[c], 1);
  }
}

__global__ void prep_dis_kernel(const float* __restrict__ deg, float* __restrict__ dis, int n) {
  int i = blockIdx.x * blockDim.x + threadIdx.x;
  if (i < n) {
    float d = deg[i];
    dis[i] = d > 0.f ? rsqrtf(fmaxf(d, 1e-12f)) : 0.f;
  }
}

// block sums of cnt chunks (256 elems/block)
__global__ void prep_scanA_kernel(const int* __restrict__ cnt, int* __restrict__ partial, int n) {
  __shared__ int sd[256];
  int tid = threadIdx.x;
  int i = blockIdx.x * 256 + tid;
  sd[tid] = (i < n) ? cnt[i] : 0;
  __syncthreads();
  for (int s = 128; s > 0; s >>= 1) {
    if (tid < s) sd[tid] += sd[tid + s];
    __syncthreads();
  }
  if (tid == 0) partial[blockIdx.x] = sd[0];
}

// exclusive scan of block partials (nb <= 256), plus ptr[n] = total
__global__ void prep_scanB_kernel(int* __restrict__ partial, int* __restrict__ ptr, int nb, int n) {
  __shared__ int sd[256];
  int tid = threadIdx.x;
  int v = (tid < nb) ? partial[tid] : 0;
  sd[tid] = v;
  __syncthreads();
  for (int offd = 1; offd < 256; offd <<= 1) {
    int t = (tid >= offd) ? sd[tid - offd] : 0;
    __syncthreads();
    sd[tid] += t;
    __syncthreads();
  }
  if (tid < nb) partial[tid] = sd[tid] - v;   // exclusive
  if (tid == 255) ptr[n] = sd[255];
}

// per-chunk exclusive scan + block offset -> ptr, pos
__global__ void prep_scanC_kernel(const int* __restrict__ cnt, const int* __restrict__ partial,
                                  int* __restrict__ ptr, int* __restrict__ pos, int n) {
  __shared__ int sd[256];
  int tid = threadIdx.x;
  int i = blockIdx.x * 256 + tid;
  int v = (i < n) ? cnt[i] : 0;
  sd[tid] = v;
  __syncthreads();
  for (int offd = 1; offd < 256; offd <<= 1) {
    int t = (tid >= offd) ? sd[tid - offd] : 0;
    __syncthreads();
    sd[tid] += t;
    __syncthreads();
  }
  if (i < n) {
    int p = partial[blockIdx.x] + sd[tid] - v;
    ptr[i] = p;
    pos[i] = p;
  }
}

// place + norm fused: wsrt[slot] = dis[r]*w*dis[c]
__global__ void prep_place_kernel(const int* __restrict__ row32, const int* __restrict__ col32,
                                  const float* __restrict__ ew, const float* __restrict__ dis,
                                  int* __restrict__ pos, int* __restrict__ srcs,
                                  float* __restrict__ wsrt, int E) {
  int e = blockIdx.x * blockDim.x + threadIdx.x;
  if (e < E) {
    int r = row32[e], c = col32[e];
    int slot = atomicAdd(&pos[c], 1);
    srcs[slot] = r;
    wsrt[slot] = dis[r] * ew[e] * dis[c];
  }
}

// ---------------- propagation hop, d=128, fused y-add (+ optional ELU) ----------------
// One FULL wave (64 lanes) per node. Lanes split in two halves (32 lanes = one
// float4-slot each covering all 128 features); each half processes a contiguous
// half of the node's edge range with 4-edge unrolling (4 gathers in flight),
// then halves combine via shfl_xor(32).
// sout[n][:] = maybeELU( y[n][:] + sum_j w_j * sin[src_j][:] )
template <int TAG, bool ELU>
__global__ void hop128_kernel(const float* __restrict__ sin_, const float* __restrict__ y,
                              const int* __restrict__ ptr, const int* __restrict__ srcs,
                              const float* __restrict__ w, float* __restrict__ sout, int n) {
  const int lane = threadIdx.x & 63;
  const int wid = threadIdx.x >> 6;        // 4 waves per 256-thread block
  const int half = lane >> 5;              // 0 or 1
  const int f4 = lane & 31;                // float4 slot: 32 x float4 = 128 floats
  const int node = blockIdx.x * 4 + wid;
  if (node >= n) return;
  const float4* s4 = (const float4*)sin_;

  const int b = ptr[node], e = ptr[node + 1];
  const int len = e - b;
  const int c0 = (len + 1) >> 1;           // ceil half for half 0
  const int js = half ? (b + c0) : b;
  const int je = half ? e : (b + c0);

  float4 acc;
  if (half == 0) acc = ((const float4*)y)[(size_t)node * 32 + f4];
  else           acc = make_float4(0.f, 0.f, 0.f, 0.f);

  int j = js;
  for (; j + 3 < je; j += 4) {
    int s0 = srcs[j], s1 = srcs[j + 1], s2 = srcs[j + 2], s3 = srcs[j + 3];
    float w0 = w[j], w1 = w[j + 1], w2 = w[j + 2], w3 = w[j + 3];
    float4 v0 = s4[(size_t)s0 * 32 + f4];
    float4 v1 = s4[(size_t)s1 * 32 + f4];
    float4 v2 = s4[(size_t)s2 * 32 + f4];
    float4 v3 = s4[(size_t)s3 * 32 + f4];
    acc.x += w0 * v0.x + w1 * v1.x + w2 * v2.x + w3 * v3.x;
    acc.y += w0 * v0.y + w1 * v1.y + w2 * v2.y + w3 * v3.y;
    acc.z += w0 * v0.z + w1 * v1.z + w2 * v2.z + w3 * v3.z;
    acc.w += w0 * v0.w + w1 * v1.w + w2 * v2.w + w3 * v3.w;
  }
  for (; j < je; ++j) {
    float w0 = w[j];
    float4 v0 = s4[(size_t)srcs[j] * 32 + f4];
    acc.x += w0 * v0.x; acc.y += w0 * v0.y; acc.z += w0 * v0.z; acc.w += w0 * v0.w;
  }

  // combine the two halves (lane ^ 32 holds the other half's partial for same f4)
  acc.x += __shfl_xor(acc.x, 32);
  acc.y += __shfl_xor(acc.y, 32);
  acc.z += __shfl_xor(acc.z, 32);
  acc.w += __shfl_xor(acc.w, 32);

  if (half == 0) {
    if (ELU) {
      acc.x = acc.x > 0.f ? acc.x : expm1f(acc.x);
      acc.y = acc.y > 0.f ? acc.y : expm1f(acc.y);
      acc.z = acc.z > 0.f ? acc.z : expm1f(acc.z);
      acc.w = acc.w > 0.f ? acc.w : expm1f(acc.w);
    }
    ((float4*)sout)[(size_t)node * 32 + f4] = acc;
  }
}

// d=10 hop with fused add:  out[n][f] = ybuf[n*64 + yOff + f] + sum_e w * z[s*zStride + zOff + f]
// One wave per node; edges split over 4 sub-groups of 16 lanes (f = lane&15),
// combined via shfl_xor(16) + shfl_xor(32).
template <int TAG>
__global__ void hop10_kernel(const float* __restrict__ z, int zStride, int zOff,
                             const float* __restrict__ ybuf, int yOff,
                             const int* __restrict__ ptr, const int* __restrict__ srcs,
                             const float* __restrict__ wsrt, float* __restrict__ out, int n) {
  const int lane = threadIdx.x & 63;
  const int wid = threadIdx.x >> 6;
  const int sub = lane >> 4;               // 0..3
  const int f = lane & 15;
  const int node = blockIdx.x * 4 + wid;
  if (node >= n) return;

  const int b = ptr[node], e = ptr[node + 1];
  const int len = e - b;
  const int js = b + (len * sub) / 4;
  const int je = b + (len * (sub + 1)) / 4;

  float acc = 0.f;
  if (f < CDIM) {
    if (sub == 0) acc = ybuf[(size_t)node * 64 + yOff + f];
    int j = js;
    for (; j + 1 < je; j += 2) {
      int s0 = srcs[j], s1 = srcs[j + 1];
      float w0 = wsrt[j], w1 = wsrt[j + 1];
      float v0 = z[(size_t)s0 * zStride + zOff + f];
      float v1 = z[(size_t)s1 * zStride + zOff + f];
      acc += w0 * v0 + w1 * v1;
    }
    if (j < je) acc += wsrt[j] * z[(size_t)srcs[j] * zStride + zOff + f];
  }
  acc += __shfl_xor(acc, 16);
  acc += __shfl_xor(acc, 32);
  if (sub == 0 && f < CDIM) out[(size_t)node * CDIM + f] = acc;
}

// ---------------- dense GEMM ----------------
// out[n, c] = sum_k X[n,k] * B[k,c] (+bias)   64x64 tile, 256 threads, 4x4/thread
// BMODE 0: B[k,c] = W[k*128 + c], 128 cols (one hop-matrix slice)
// BMODE 1: B[k,c] = W3[(c/10)*K_DIM*10 + k*10 + c%10]  (c<60; 6 matrices concatenated)
template <int TAG, int K_DIM, int BMODE, bool ADD_BIAS>
__global__ void gemm_kernel(const float* __restrict__ X, const float* __restrict__ W,
                            const float* __restrict__ bias, float* __restrict__ out,
                            int n, int ostride) {
  __shared__ float xt[32][68];   // [k][node], padded
  __shared__ float bt[32][64];   // [k][col]
  const int tid = threadIdx.x;
  const int tx = tid & 15;       // node group
  const int ty = tid >> 4;       // col group
  const int n0 = blockIdx.x * 64;
  const int c0 = blockIdx.y * 64;
  float acc[4][4];
#pragma unroll
  for (int i = 0; i < 4; ++i)
#pragma unroll
    for (int j = 0; j < 4; ++j) acc[i][j] = 0.f;

  for (int k0 = 0; k0 < K_DIM; k0 += 32) {
#pragma unroll
    for (int i = 0; i < 8; ++i) {
      int idx = tid + i * 256;
      int nl = idx >> 5, kl = idx & 31;
      int nn = n0 + nl, kg = k0 + kl;
      float v = 0.f;
      if (nn < n && kg < K_DIM) v = X[(size_t)nn * K_DIM + kg];
      xt[kl][nl] = v;
    }
#pragma unroll
    for (int i = 0; i < 8; ++i) {
      int idx = tid + i * 256;
      int kl = idx >> 6, cl = idx & 63;
      int kg = k0 + kl, c = c0 + cl;
      float v = 0.f;
      if (BMODE == 0) {
        if (kg < K_DIM) v = W[(size_t)kg * 128 + c];
      } else {
        if (kg < K_DIM && cl < 6 * CDIM)
          v = W[(size_t)(cl / CDIM) * (K_DIM * CDIM) + (size_t)kg * CDIM + (cl % CDIM)];
      }
      bt[kl][cl] = v;
    }
    __syncthreads();
#pragma unroll
    for (int kk = 0; kk < 32; ++kk) {
      float4 xv = *(const float4*)&xt[kk][tx * 4];
      float4 bv = *(const float4*)&bt[kk][ty * 4];
      acc[0][0] += xv.x * bv.x; acc[0][1] += xv.x * bv.y; acc[0][2] += xv.x * bv.z; acc[0][3] += xv.x * bv.w;
      acc[1][0] += xv.y * bv.x; acc[1][1] += xv.y * bv.y; acc[1][2] += xv.y * bv.z; acc[1][3] += xv.y * bv.w;
      acc[2][0] += xv.z * bv.x; acc[2][1] += xv.z * bv.y; acc[2][2] += xv.z * bv.z; acc[2][3] += xv.z * bv.w;
      acc[3][0] += xv.w * bv.x; acc[3][1] += xv.w * bv.y; acc[3][2] += xv.w * bv.z; acc[3][3] += xv.w * bv.w;
    }
    __syncthreads();
  }
#pragma unroll
  for (int i = 0; i < 4; ++i) {
    int nn = n0 + tx * 4 + i;
    if (nn >= n) continue;
#pragma unroll
    for (int j = 0; j < 4; ++j) {
      int c = c0 + ty * 4 + j;
      float r = acc[i][j];
      if (ADD_BIAS) {
        if (BMODE == 0) r += bias[c];
        else if (c < CDIM) r += bias[c];
      }
      out[(size_t)nn * ostride + c] = r;
    }
  }
}

// ---------------- host ----------------

extern "C" void kernel_launch(void* const* d_in, const int* in_sizes, int n_in,
                              void* d_out, int out_size, void* d_ws, size_t ws_size,
                              hipStream_t stream) {
  const float* x  = (const float*)d_in[0];
  const int*   ei = (const int*)d_in[1];
  const float* ew = (const float*)d_in[2];
  const float* W1 = (const float*)d_in[3];
  const float* b1 = (const float*)d_in[4];
  const float* W2 = (const float*)d_in[5];
  const float* b2 = (const float*)d_in[6];
  const float* W3 = (const float*)d_in[7];
  const float* b3 = (const float*)d_in[8];
  float* out = (float*)d_out;

  const int N = N_NODES, E = N_EDGES;
  char* base = (char*)d_ws;
  size_t off = 0;
  auto alloc = [&](size_t bytes) -> char* {
    char* p = base + off;
    off += (bytes + 255) & ~(size_t)255;
    return p;
  };
  float* bufA = (float*)alloc((size_t)N * 128 * 4);
  float* bufB = (float*)alloc((size_t)N * 128 * 4);
  float* bufC = (float*)alloc((size_t)N * 128 * 4);
  float* bufD = (float*)alloc((size_t)N * 128 * 4);
  int*   ptrA = (int*)alloc((size_t)(N + 1) * 4);
  int*   pos  = (int*)alloc((size_t)N * 4);
  int*   srcs = (int*)alloc((size_t)E * 4);
  float* wsrt = (float*)alloc((size_t)E * 4);
  int*   part = (int*)alloc(256 * 4);

  // Preprocessing transients overlay bufA (bufA first written after preprocessing).
  char* t = (char*)bufA;
  int*   row32 = (int*)t;   t += (size_t)E * 4;
  int*   col32 = (int*)t;   t += (size_t)E * 4;
  float* deg   = (float*)t; t += (size_t)N * 4;
  float* dis   = (float*)t; t += (size_t)N * 4;
  int*   cnt   = (int*)t;   t += (size_t)N * 4;

  hipMemsetAsync(deg, 0, (size_t)N * 4, stream);
  hipMemsetAsync(cnt, 0, (size_t)N * 4, stream);

  const int eb = (E + 255) / 256;
  const int nb = (N + 255) / 256;   // 196
  prep_convert_kernel<<<eb, 256, 0, stream>>>(ei, ew, row32, col32, deg, cnt, E);
  prep_dis_kernel<<<nb, 256, 0, stream>>>(deg, dis, N);
  prep_scanA_kernel<<<nb, 256, 0, stream>>>(cnt, part, N);
  prep_scanB_kernel<<<1, 256, 0, stream>>>(part, ptrA, nb, N);
  prep_scanC_kernel<<<nb, 256, 0, stream>>>(cnt, part, ptrA, pos, N);
  prep_place_kernel<<<eb, 256, 0, stream>>>(row32, col32, ew, dis, pos, srcs, wsrt, E);

  const dim3 gemmGrid((N + 63) / 64, 2);
  const int hopBlocks = (N + 3) / 4;   // 1 wave per node, 4 waves per block

  // ===== layer 1: in = x (K=100), Horner: s=y5; s=A*s+y_k; ELU at k=0 =====
  {
    const float* in = x;
    float* Y = bufA; float* P = bufB; float* Q = bufC;
    gemm_kernel<15, F_IN_D, 0, false><<<gemmGrid, 256, 0, stream>>>(in, W1 + (size_t)5 * F_IN_D * 128, b1, P, N, 128);
    gemm_kernel<14, F_IN_D, 0, false><<<gemmGrid, 256, 0, stream>>>(in, W1 + (size_t)4 * F_IN_D * 128, b1, Y, N, 128);
    hop128_kernel<14, false><<<hopBlocks, 256, 0, stream>>>(P, Y, ptrA, srcs, wsrt, Q, N);
    { float* tmp = P; P = Q; Q = tmp; }
    gemm_kernel<13, F_IN_D, 0, false><<<gemmGrid, 256, 0, stream>>>(in, W1 + (size_t)3 * F_IN_D * 128, b1, Y, N, 128);
    hop128_kernel<13, false><<<hopBlocks, 256, 0, stream>>>(P, Y, ptrA, srcs, wsrt, Q, N);
    { float* tmp = P; P = Q; Q = tmp; }
    gemm_kernel<12, F_IN_D, 0, false><<<gemmGrid, 256, 0, stream>>>(in, W1 + (size_t)2 * F_IN_D * 128, b1, Y, N, 128);
    hop128_kernel<12, false><<<hopBlocks, 256, 0, stream>>>(P, Y, ptrA, srcs, wsrt, Q, N);
    { float* tmp = P; P = Q; Q = tmp; }
    gemm_kernel<11, F_IN_D, 0, false><<<gemmGrid, 256, 0, stream>>>(in, W1 + (size_t)1 * F_IN_D * 128, b1, Y, N, 128);
    hop128_kernel<11, false><<<hopBlocks, 256, 0, stream>>>(P, Y, ptrA, srcs, wsrt, Q, N);
    { float* tmp = P; P = Q; Q = tmp; }
    gemm_kernel<10, F_IN_D, 0, true><<<gemmGrid, 256, 0, stream>>>(in, W1, b1, Y, N, 128);
    hop128_kernel<10, true><<<hopBlocks, 256, 0, stream>>>(P, Y, ptrA, srcs, wsrt, Q, N);
    // result (h1) in Q == bufC
  }

  // ===== layer 2: in = bufC (K=128) =====
  {
    const float* in = bufC;
    float* Y = bufA; float* P = bufB; float* Q = bufD;
    gemm_kernel<25, HDIM, 0, false><<<gemmGrid, 256, 0, stream>>>(in, W2 + (size_t)5 * HDIM * 128, b2, P, N, 128);
    gemm_kernel<24, HDIM, 0, false><<<gemmGrid, 256, 0, stream>>>(in, W2 + (size_t)4 * HDIM * 128, b2, Y, N, 128);
    hop128_kernel<24, false><<<hopBlocks, 256, 0, stream>>>(P, Y, ptrA, srcs, wsrt, Q, N);
    { float* tmp = P; P = Q; Q = tmp; }
    gemm_kernel<23, HDIM, 0, false><<<gemmGrid, 256, 0, stream>>>(in, W2 + (size_t)3 * HDIM * 128, b2, Y, N, 128);
    hop128_kernel<23, false><<<hopBlocks, 256, 0, stream>>>(P, Y, ptrA, srcs, wsrt, Q, N);
    { float* tmp = P; P = Q; Q = tmp; }
    gemm_kernel<22, HDIM, 0, false><<<gemmGrid, 256, 0, stream>>>(in, W2 + (size_t)2 * HDIM * 128, b2, Y, N, 128);
    hop128_kernel<22, false><<<hopBlocks, 256, 0, stream>>>(P, Y, ptrA, srcs, wsrt, Q, N);
    { float* tmp = P; P = Q; Q = tmp; }
    gemm_kernel<21, HDIM, 0, false><<<gemmGrid, 256, 0, stream>>>(in, W2 + (size_t)1 * HDIM * 128, b2, Y, N, 128);
    hop128_kernel<21, false><<<hopBlocks, 256, 0, stream>>>(P, Y, ptrA, srcs, wsrt, Q, N);
    { float* tmp = P; P = Q; Q = tmp; }
    gemm_kernel<20, HDIM, 0, true><<<gemmGrid, 256, 0, stream>>>(in, W2, b2, Y, N, 128);
    hop128_kernel<20, true><<<hopBlocks, 256, 0, stream>>>(P, Y, ptrA, srcs, wsrt, Q, N);
    // result (h2) in Q == bufD
  }

  // ===== layer 3: in = bufD, 128 -> 10 via Horner on projected y (BMODE1) =====
  {
    const float* in = bufD;
    float* ybuf = bufA;                                 // [N][64]: c = k*10+f
    float* z0 = bufB;
    float* z1 = (float*)((char*)bufB + (size_t)N * 16 * 4);
    dim3 g3((N + 63) / 64, 1);
    gemm_kernel<30, HDIM, 1, true><<<g3, 256, 0, stream>>>(in, W3, b3, ybuf, N, 64);
    hop10_kernel<35><<<hopBlocks, 256, 0, stream>>>(ybuf, 64, 50, ybuf, 40, ptrA, srcs, wsrt, z0, N);
    hop10_kernel<34><<<hopBlocks, 256, 0, stream>>>(z0, 10, 0, ybuf, 30, ptrA, srcs, wsrt, z1, N);
    hop10_kernel<33><<<hopBlocks, 256, 0, stream>>>(z1, 10, 0, ybuf, 20, ptrA, srcs, wsrt, z0, N);
    hop10_kernel<32><<<hopBlocks, 256, 0, stream>>>(z0, 10, 0, ybuf, 10, ptrA, srcs, wsrt, z1, N);
    hop10_kernel<31><<<hopBlocks, 256, 0, stream>>>(z1, 10, 0, ybuf, 0, ptrA, srcs, wsrt, out, N);
  }

  (void)in_sizes; (void)n_in; (void)out_size; (void)ws_size;
}